// Round 2
// baseline (4370.458 us; speedup 1.0000x reference)
//
#include <hip/hip_runtime.h>
#include <hip/hip_bf16.h>

typedef __hip_bfloat16 bf16;
typedef short bf16x8 __attribute__((ext_vector_type(8)));
typedef float f32x4 __attribute__((ext_vector_type(4)));

#define B_ 2
#define T_ 2048
#define C_ 768
#define H_ 12
#define HS_ 64
#define M_ (B_ * T_)           // 4096
#define SCALE_ 0.036084391824351615f  // 1/sqrt(768)

__device__ inline short bf16bits(float f) {
    union { bf16 b; short s; } u; u.b = __float2bfloat16(f); return u.s;
}

template<typename TIN> __device__ inline bf16x8 load_frag(const TIN* p);

template<> __device__ inline bf16x8 load_frag<float>(const float* p) {
    bf16x8 r;
#pragma unroll
    for (int i = 0; i < 8; ++i) r[i] = bf16bits(p[i]);
    return r;
}
template<> __device__ inline bf16x8 load_frag<bf16>(const bf16* p) {
    return *(const bf16x8*)p;
}

__device__ inline void store_val(float* p, float v)  { *p = v; }
__device__ inline void store_val(bf16* p, float v)   { *p = __float2bfloat16(v); }

// Y[m][n] = sum_k X[m][k] * W[n][k] + bias[n]   (torch Linear: y = x @ W.T + b)
// One wave -> 16x64 output strip. M,N mult of 64; K mult of 32.
template<typename TIN, typename TOUT>
__global__ __launch_bounds__(256) void gemm_xwT(
    const TIN* __restrict__ X, const float* __restrict__ W,
    const float* __restrict__ bias, TOUT* __restrict__ Y,
    int M, int N, int K)
{
    const int wave = threadIdx.x >> 6;
    const int lane = threadIdx.x & 63;
    const int m0   = blockIdx.x * 64 + wave * 16;
    const int n0   = blockIdx.y * 64;
    const int nl   = lane & 15;
    const int kq   = (lane >> 4) * 8;          // quad k-offset (A/B operand layout)
    const int row  = m0 + nl;

    f32x4 acc[4] = {f32x4{0,0,0,0}, f32x4{0,0,0,0}, f32x4{0,0,0,0}, f32x4{0,0,0,0}};

    for (int k0 = 0; k0 < K; k0 += 32) {
        bf16x8 a = load_frag<TIN>(X + (size_t)row * K + k0 + kq);
#pragma unroll
        for (int t = 0; t < 4; ++t) {
            const int col = n0 + t * 16 + nl;
            bf16x8 b = load_frag<float>(W + (size_t)col * K + k0 + kq);
            acc[t] = __builtin_amdgcn_mfma_f32_16x16x32_bf16(a, b, acc[t], 0, 0, 0);
        }
    }

    const int rbase = m0 + (lane >> 4) * 4;    // C/D layout: row=(lane>>4)*4+r, col=lane&15
#pragma unroll
    for (int t = 0; t < 4; ++t) {
        const int col = n0 + t * 16 + nl;
        const float bv = bias[col];
#pragma unroll
        for (int r = 0; r < 4; ++r) {
            store_val(Y + (size_t)(rbase + r) * N + col, acc[t][r] + bv);
        }
    }
}

// One block per (b, h, q): s[k] = U_q . X_k (k<=q), causal softmax, y = P.V
__global__ __launch_bounds__(256) void attn_kernel(
    const bf16* __restrict__ U, const float* __restrict__ X,
    const bf16* __restrict__ V, bf16* __restrict__ Y)
{
    __shared__ float qs[HS_];
    __shared__ float s[T_];
    __shared__ float red[4];
    __shared__ float pc[4][HS_];
    __shared__ float m_sh, l_sh;

    const int q   = blockIdx.x;
    const int h   = blockIdx.y;
    const int b   = blockIdx.z;
    const int tid = threadIdx.x;
    const int lane = tid & 63;
    const int wid  = tid >> 6;
    const size_t base = (size_t)b * T_ * C_ + (size_t)h * HS_;

    if (tid < HS_) qs[tid] = __bfloat162float(U[base + (size_t)q * C_ + tid]);
    __syncthreads();

    // Phase A: scores for k in [0, q]
    for (int k = tid; k <= q; k += 256) {
        const float* xr = X + base + (size_t)k * C_;
        float acc = 0.f;
#pragma unroll
        for (int d = 0; d < HS_; ++d) acc += qs[d] * xr[d];
        s[k] = acc * SCALE_;
    }
    __syncthreads();

    // Phase B1: max
    float m = -1e30f;
    for (int k = tid; k <= q; k += 256) m = fmaxf(m, s[k]);
#pragma unroll
    for (int off = 32; off; off >>= 1) m = fmaxf(m, __shfl_down(m, off, 64));
    if (lane == 0) red[wid] = m;
    __syncthreads();
    if (tid == 0) m_sh = fmaxf(fmaxf(red[0], red[1]), fmaxf(red[2], red[3]));
    __syncthreads();

    // Phase B2: exp + sum
    const float msv = m_sh;
    float lsum = 0.f;
    for (int k = tid; k <= q; k += 256) {
        float e = __expf(s[k] - msv);
        s[k] = e;
        lsum += e;
    }
#pragma unroll
    for (int off = 32; off; off >>= 1) lsum += __shfl_down(lsum, off, 64);
    if (lane == 0) red[wid] = lsum;
    __syncthreads();
    if (tid == 0) l_sh = red[0] + red[1] + red[2] + red[3];
    __syncthreads();
    const float inv_l = 1.f / l_sh;

    // Phase C: y[d] = (1/l) * sum_k s[k] * V[k][d]
    const int d = lane;       // 0..63
    const int g = wid;        // 0..3
    float acc = 0.f;
    for (int k = g; k <= q; k += 4) {
        acc += s[k] * __bfloat162float(V[base + (size_t)k * C_ + d]);
    }
    pc[g][d] = acc;
    __syncthreads();
    if (g == 0) {
        float y = (pc[0][d] + pc[1][d] + pc[2][d] + pc[3][d]) * inv_l;
        Y[base + (size_t)q * C_ + d] = __float2bfloat16(y);
    }
}

extern "C" void kernel_launch(void* const* d_in, const int* in_sizes, int n_in,
                              void* d_out, int out_size, void* d_ws, size_t ws_size,
                              hipStream_t stream) {
    const float* x   = (const float*)d_in[0];
    const float* w_u = (const float*)d_in[1];
    const float* b_u = (const float*)d_in[2];
    const float* w_v = (const float*)d_in[3];
    const float* b_v = (const float*)d_in[4];
    const float* w_p = (const float*)d_in[5];
    const float* b_p = (const float*)d_in[6];
    float* out = (float*)d_out;

    char* ws = (char*)d_ws;
    const size_t slab = (size_t)M_ * C_ * sizeof(bf16);  // 6291456 B
    bf16* U  = (bf16*)(ws);
    bf16* V  = (bf16*)(ws + slab);
    bf16* Yw = (bf16*)(ws + 2 * slab);

    dim3 blk(256);
    dim3 ggrid(M_ / 64, C_ / 64);   // (64, 12)
    gemm_xwT<float, bf16><<<ggrid, blk, 0, stream>>>(x, w_u, b_u, U, M_, C_, C_);
    gemm_xwT<float, bf16><<<ggrid, blk, 0, stream>>>(x, w_v, b_v, V, M_, C_, C_);

    dim3 agrid(T_, H_, B_);
    attn_kernel<<<agrid, blk, 0, stream>>>(U, x, V, Yw);

    gemm_xwT<bf16, float><<<ggrid, blk, 0, stream>>>(Yw, w_p, b_p, out, M_, C_, C_);
}

// Round 3
// 568.449 us; speedup vs baseline: 7.6884x; 7.6884x over previous
//
#include <hip/hip_runtime.h>
#include <hip/hip_bf16.h>

typedef __hip_bfloat16 bf16;
typedef short bf16x8 __attribute__((ext_vector_type(8)));
typedef float f32x4 __attribute__((ext_vector_type(4)));
typedef float f32x8 __attribute__((ext_vector_type(8)));

#define B_ 2
#define T_ 2048
#define C_ 768
#define H_ 12
#define HS_ 64
#define M_ (B_ * T_)           // 4096
#define SCALE_ 0.036084391824351615f  // 1/sqrt(768)

__device__ inline short bf16bits(float f) {
    union { bf16 b; short s; } u; u.b = __float2bfloat16(f); return u.s;
}

template<typename TIN> __device__ inline bf16x8 load_frag(const TIN* p);
template<> __device__ inline bf16x8 load_frag<float>(const float* p) {
    f32x8 f = *(const f32x8*)p;
    bf16x8 r;
#pragma unroll
    for (int i = 0; i < 8; ++i) r[i] = bf16bits(f[i]);
    return r;
}
template<> __device__ inline bf16x8 load_frag<bf16>(const bf16* p) {
    return *(const bf16x8*)p;
}

__device__ inline void store_val(float* p, float v)  { *p = v; }
__device__ inline void store_val(bf16* p, float v)   { *p = __float2bfloat16(v); }

// Y[m][n] = sum_k X[m][k] * W[n][k] + bias[n]   (torch Linear: y = x @ W.T + b)
// One wave -> 16x64 output strip. VT=1: write output per-head transposed
// Vt[b][h][d][t] (bf16) instead of row-major.
template<typename TIN, typename TOUT, int VT>
__global__ __launch_bounds__(256) void gemm_xwT(
    const TIN* __restrict__ X, const float* __restrict__ W,
    const float* __restrict__ bias, TOUT* __restrict__ Y,
    int M, int N, int K)
{
    const int wave = threadIdx.x >> 6;
    const int lane = threadIdx.x & 63;
    const int m0   = blockIdx.x * 64 + wave * 16;
    const int n0   = blockIdx.y * 64;
    const int nl   = lane & 15;
    const int kq   = (lane >> 4) * 8;          // quad k-offset (A/B operand layout)
    const int row  = m0 + nl;

    f32x4 acc[4] = {f32x4{0,0,0,0}, f32x4{0,0,0,0}, f32x4{0,0,0,0}, f32x4{0,0,0,0}};

    for (int k0 = 0; k0 < K; k0 += 32) {
        bf16x8 a = load_frag<TIN>(X + (size_t)row * K + k0 + kq);
#pragma unroll
        for (int t = 0; t < 4; ++t) {
            const int col = n0 + t * 16 + nl;
            bf16x8 b = load_frag<float>(W + (size_t)col * K + k0 + kq);
            acc[t] = __builtin_amdgcn_mfma_f32_16x16x32_bf16(a, b, acc[t], 0, 0, 0);
        }
    }

    const int rbase = m0 + (lane >> 4) * 4;    // C/D layout: row=(lane>>4)*4+r, col=lane&15
#pragma unroll
    for (int t = 0; t < 4; ++t) {
        const int col = n0 + t * 16 + nl;
        const float bv = bias[col];
#pragma unroll
        for (int r = 0; r < 4; ++r) {
            const float v = acc[t][r] + bv;
            if (VT) {
                // token m -> (b, t); channel col -> (h, d); Vt[((b*H+h)*HS+d)*T + t]
                const int mrow = rbase + r;
                const int bb = mrow / T_, tt = mrow % T_;
                const int hh = col / HS_,  dd = col % HS_;
                ((bf16*)Y)[(((size_t)bb * H_ + hh) * HS_ + dd) * T_ + tt] = __float2bfloat16(v);
            } else {
                store_val(Y + (size_t)(rbase + r) * N + col, v);
            }
        }
    }
}

// Flash attention: one block per (b, h, 64-query tile); 4 waves x 16 query rows.
// Q = U rows (bf16), K = raw x rows (fp32 -> bf16 in-register), V = Vt[b][h][d][t].
__global__ __launch_bounds__(256) void flash_attn(
    const bf16* __restrict__ U, const float* __restrict__ X,
    const bf16* __restrict__ Vt, bf16* __restrict__ Y)
{
    __shared__ __align__(16) short lds_p[4][16][80];   // per-wave P tile, 16B-aligned rows

    const int qt   = (T_ / 64 - 1) - blockIdx.x;  // heavy tiles first
    const int h    = blockIdx.y;
    const int b    = blockIdx.z;
    const int wave = threadIdx.x >> 6;
    const int lane = threadIdx.x & 63;
    const int nl   = lane & 15;
    const int quad = lane >> 4;
    const int kq   = quad * 8;

    const size_t xbase  = (size_t)b * T_ * C_ + (size_t)h * HS_;
    const size_t vtbase = ((size_t)(b * H_ + h)) * HS_ * T_;
    const int q0 = qt * 64 + wave * 16;           // this wave's first query row

    // Q A-fragments (k chunks 0..31, 32..63), held in registers for all K-tiles
    bf16x8 qa[2];
    {
        const bf16* qp = U + xbase + (size_t)(q0 + nl) * C_;
        qa[0] = *(const bf16x8*)(qp + kq);
        qa[1] = *(const bf16x8*)(qp + 32 + kq);
    }

    f32x4 o[4] = {f32x4{0,0,0,0}, f32x4{0,0,0,0}, f32x4{0,0,0,0}, f32x4{0,0,0,0}};
    float mrow[4] = {-1e30f, -1e30f, -1e30f, -1e30f};
    float lrow[4] = {0.f, 0.f, 0.f, 0.f};

    for (int kt = 0; kt <= qt; ++kt) {
        // ---- S = Q.K^T (16q x 64k), 8 MFMA
        f32x4 s[4] = {f32x4{0,0,0,0}, f32x4{0,0,0,0}, f32x4{0,0,0,0}, f32x4{0,0,0,0}};
#pragma unroll
        for (int t = 0; t < 4; ++t) {
            const float* kp = X + xbase + (size_t)(kt * 64 + t * 16 + nl) * C_;
#pragma unroll
            for (int c = 0; c < 2; ++c) {
                bf16x8 kb = load_frag<float>(kp + c * 32 + kq);
                s[t] = __builtin_amdgcn_mfma_f32_16x16x32_bf16(qa[c], kb, s[t], 0, 0, 0);
            }
        }

        // ---- scale + causal mask (diagonal tile only)
        if (kt == qt) {
#pragma unroll
            for (int t = 0; t < 4; ++t) {
                const int gk = kt * 64 + t * 16 + nl;
#pragma unroll
                for (int r = 0; r < 4; ++r) {
                    const int gq = q0 + quad * 4 + r;
                    s[t][r] = (gk > gq) ? -1e30f : s[t][r] * SCALE_;
                }
            }
        } else {
#pragma unroll
            for (int t = 0; t < 4; ++t)
#pragma unroll
                for (int r = 0; r < 4; ++r) s[t][r] *= SCALE_;
        }

        // ---- online softmax stats (row r lives on the 16-lane group: shfl_xor 1,2,4,8)
        float alpha[4];
#pragma unroll
        for (int r = 0; r < 4; ++r) {
            float v = fmaxf(fmaxf(s[0][r], s[1][r]), fmaxf(s[2][r], s[3][r]));
            v = fmaxf(v, __shfl_xor(v, 1, 64));
            v = fmaxf(v, __shfl_xor(v, 2, 64));
            v = fmaxf(v, __shfl_xor(v, 4, 64));
            v = fmaxf(v, __shfl_xor(v, 8, 64));
            const float mnew = fmaxf(mrow[r], v);
            alpha[r] = __expf(mrow[r] - mnew);
            mrow[r] = mnew;
        }
        float rsum[4];
#pragma unroll
        for (int r = 0; r < 4; ++r) {
            float acc = 0.f;
#pragma unroll
            for (int t = 0; t < 4; ++t) {
                const float p = __expf(s[t][r] - mrow[r]);
                s[t][r] = p;
                acc += p;
            }
            acc += __shfl_xor(acc, 1, 64);
            acc += __shfl_xor(acc, 2, 64);
            acc += __shfl_xor(acc, 4, 64);
            acc += __shfl_xor(acc, 8, 64);
            lrow[r] = lrow[r] * alpha[r] + acc;
        }
#pragma unroll
        for (int t = 0; t < 4; ++t)
#pragma unroll
            for (int r = 0; r < 4; ++r) o[t][r] *= alpha[r];

        // ---- P: C-layout -> A-layout via per-wave LDS tile
#pragma unroll
        for (int t = 0; t < 4; ++t)
#pragma unroll
            for (int r = 0; r < 4; ++r)
                lds_p[wave][quad * 4 + r][t * 16 + nl] = bf16bits(s[t][r]);
        __syncthreads();

        bf16x8 pa[2];
        pa[0] = *(const bf16x8*)&lds_p[wave][nl][kq];
        pa[1] = *(const bf16x8*)&lds_p[wave][nl][32 + kq];

        // ---- O += P.V  (V^T fragments: contiguous along keys)
#pragma unroll
        for (int t = 0; t < 4; ++t) {
            const bf16* vp = Vt + vtbase + (size_t)(t * 16 + nl) * T_ + kt * 64;
#pragma unroll
            for (int c = 0; c < 2; ++c) {
                bf16x8 vb = *(const bf16x8*)(vp + c * 32 + kq);
                o[t] = __builtin_amdgcn_mfma_f32_16x16x32_bf16(pa[c], vb, o[t], 0, 0, 0);
            }
        }
        __syncthreads();
    }

    // ---- epilogue: y = O / l, write token-major for the proj GEMM
#pragma unroll
    for (int r = 0; r < 4; ++r) {
        const float inv_l = 1.f / lrow[r];
        const size_t yrow = xbase + (size_t)(q0 + quad * 4 + r) * C_;
#pragma unroll
        for (int t = 0; t < 4; ++t)
            Y[yrow + t * 16 + nl] = __float2bfloat16(o[t][r] * inv_l);
    }
}

extern "C" void kernel_launch(void* const* d_in, const int* in_sizes, int n_in,
                              void* d_out, int out_size, void* d_ws, size_t ws_size,
                              hipStream_t stream) {
    const float* x   = (const float*)d_in[0];
    const float* w_u = (const float*)d_in[1];
    const float* b_u = (const float*)d_in[2];
    const float* w_v = (const float*)d_in[3];
    const float* b_v = (const float*)d_in[4];
    const float* w_p = (const float*)d_in[5];
    const float* b_p = (const float*)d_in[6];
    float* out = (float*)d_out;

    char* ws = (char*)d_ws;
    const size_t slab = (size_t)M_ * C_ * sizeof(bf16);  // 6291456 B
    bf16* U  = (bf16*)(ws);
    bf16* Vt = (bf16*)(ws + slab);
    bf16* Yw = (bf16*)(ws + 2 * slab);

    dim3 blk(256);
    dim3 ggrid(M_ / 64, C_ / 64);   // (64, 12)
    gemm_xwT<float, bf16, 0><<<ggrid, blk, 0, stream>>>(x, w_u, b_u, U, M_, C_, C_);
    gemm_xwT<float, bf16, 1><<<ggrid, blk, 0, stream>>>(x, w_v, b_v, Vt, M_, C_, C_);

    dim3 agrid(T_ / 64, H_, B_);    // (32, 12, 2)
    flash_attn<<<agrid, blk, 0, stream>>>(U, x, Vt, Yw);

    gemm_xwT<bf16, float, 0><<<ggrid, blk, 0, stream>>>(Yw, w_p, b_p, out, M_, C_, C_);
}

// Round 4
// 219.850 us; speedup vs baseline: 19.8793x; 2.5856x over previous
//
#include <hip/hip_runtime.h>
#include <hip/hip_bf16.h>

typedef __hip_bfloat16 bf16;
typedef short bf16x8 __attribute__((ext_vector_type(8)));
typedef short short4v __attribute__((ext_vector_type(4)));
typedef float f32x4 __attribute__((ext_vector_type(4)));

#define B_ 2
#define T_ 2048
#define C_ 768
#define H_ 12
#define HS_ 64
#define M_ (B_ * T_)              // 4096
#define XN_ (B_ * T_ * C_)        // 3145728
#define WN_ (C_ * C_)             // 589824
#define SCALE_ 0.036084391824351615f  // 1/sqrt(768)

__device__ inline short bf16bits(float f) {
    union { bf16 b; short s; } u; u.b = __float2bfloat16(f); return u.s;
}

__device__ inline void load_lds16(const void* g, void* l) {
    __builtin_amdgcn_global_load_lds(
        (const __attribute__((address_space(1))) unsigned int*)g,
        (__attribute__((address_space(3))) unsigned int*)l, 16, 0, 0);
}

// fp32 -> bf16 for x, w_u, w_v, w_p in one pass (4 elems/thread)
__global__ __launch_bounds__(256) void cvt_all(
    const float* __restrict__ x,  const float* __restrict__ wu,
    const float* __restrict__ wv, const float* __restrict__ wp,
    bf16* __restrict__ Xb,  bf16* __restrict__ Wub,
    bf16* __restrict__ Wvb, bf16* __restrict__ Wpb)
{
    const long e = (long)(blockIdx.x * 256 + threadIdx.x) * 4;
    const float* src; bf16* dst; long off;
    if (e < XN_)                { src = x;  dst = Xb;  off = e; }
    else if (e < XN_ + WN_)     { src = wu; dst = Wub; off = e - XN_; }
    else if (e < XN_ + 2*WN_)   { src = wv; dst = Wvb; off = e - XN_ - WN_; }
    else                        { src = wp; dst = Wpb; off = e - XN_ - 2L*WN_; }
    f32x4 v = *(const f32x4*)(src + off);
    short4v o;
#pragma unroll
    for (int i = 0; i < 4; ++i) o[i] = bf16bits(v[i]);
    *(short4v*)(dst + off) = o;
}

// Y[m][n] = sum_k A[m][k] * W[n][k] + bias[n]  (bf16 inputs, LDS-staged)
// Block: 64x64 output tile, 4 waves, K-step 64 (2 x 32-wide subtiles).
// VT=1: scatter output to Vt[b][h][d][t] (bf16) for the attention PV pass.
template<typename TOUT, int VT>
__global__ __launch_bounds__(256) void gemm_lds(
    const bf16* __restrict__ A, const bf16* __restrict__ Wb,
    const float* __restrict__ bias, TOUT* __restrict__ Y,
    int M, int N, int K)
{
    __shared__ __align__(16) short tA[2][64][32];
    __shared__ __align__(16) short tB[2][64][32];

    const int tid  = threadIdx.x;
    const int wave = tid >> 6, lane = tid & 63;
    const int nl = lane & 15, quad = lane >> 4, kq = quad * 8;
    const int m0 = blockIdx.x * 64, n0 = blockIdx.y * 64;

    const int lrow = tid >> 2, lkc = tid & 3;   // staging: row, 8-elem k-chunk
    const bf16* ga = A  + (size_t)(m0 + lrow) * K + lkc * 8;
    const bf16* gb = Wb + (size_t)(n0 + lrow) * K + lkc * 8;
    char* ldsA = (char*)&tA[0][0][0] + wave * 1024;   // lane scatter = lane*16
    char* ldsB = (char*)&tB[0][0][0] + wave * 1024;

    f32x4 acc[4] = {f32x4{0,0,0,0}, f32x4{0,0,0,0}, f32x4{0,0,0,0}, f32x4{0,0,0,0}};

    for (int k0 = 0; k0 < K; k0 += 64) {
#pragma unroll
        for (int j = 0; j < 2; ++j) {
            load_lds16(ga + k0 + j * 32, ldsA + j * 4096);
            load_lds16(gb + k0 + j * 32, ldsB + j * 4096);
        }
        __syncthreads();
#pragma unroll
        for (int j = 0; j < 2; ++j) {
            bf16x8 a = *(const bf16x8*)&tA[j][wave * 16 + nl][kq];
#pragma unroll
            for (int t = 0; t < 4; ++t) {
                bf16x8 b = *(const bf16x8*)&tB[j][t * 16 + nl][kq];
                acc[t] = __builtin_amdgcn_mfma_f32_16x16x32_bf16(a, b, acc[t], 0, 0, 0);
            }
        }
        __syncthreads();
    }

    const int rbase = m0 + wave * 16 + quad * 4;  // C/D: row=quad*4+r, col=lane&15
#pragma unroll
    for (int t = 0; t < 4; ++t) {
        const int col = n0 + t * 16 + nl;
        const float bv = bias[col];
#pragma unroll
        for (int r = 0; r < 4; ++r) {
            const float v = acc[t][r] + bv;
            if (VT) {
                const int mrow = rbase + r;
                const int bb = mrow / T_, tt = mrow % T_;
                const int hh = col / HS_,  dd = col % HS_;
                ((bf16*)Y)[(((size_t)bb * H_ + hh) * HS_ + dd) * T_ + tt] = __float2bfloat16(v);
            } else if (sizeof(TOUT) == 2) {
                ((bf16*)Y)[(size_t)(rbase + r) * N + col] = __float2bfloat16(v);
            } else {
                ((float*)Y)[(size_t)(rbase + r) * N + col] = v;
            }
        }
    }
}

// Flash attention, wave-independent (no barriers):
// block j's 4 waves take 16-query strips {j, 63-j, 64+j, 127-j} per (b,h)
// -> exactly 66 K-tile iterations per block (uniform load balance).
// No max-subtraction (softmax shift-invariant; scores << 88): no per-iter
// cross-lane ops at all. l accumulated per-lane, reduced once at the end.
__global__ __launch_bounds__(256) void flash_attn(
    const bf16* __restrict__ U, const bf16* __restrict__ Xb,
    const bf16* __restrict__ Vt, bf16* __restrict__ Y)
{
    __shared__ __align__(16) short lds_p[4][16][72];  // per-wave P tile, 144B rows

    const int j = blockIdx.x;                 // 0..31
    const int h = blockIdx.y, b = blockIdx.z;
    const int wave = threadIdx.x >> 6, lane = threadIdx.x & 63;
    const int nl = lane & 15, quad = lane >> 4, kq = quad * 8;

    const int s_idx = (wave == 0) ? j : (wave == 1) ? 63 - j
                    : (wave == 2) ? 64 + j : 127 - j;
    const int q0   = s_idx * 16;
    const int qt   = s_idx >> 2;              // last K-tile index
    const int tmax = s_idx & 3;               // live 16-col groups in diag tile

    const size_t xbase  = (size_t)b * T_ * C_ + (size_t)h * HS_;
    const size_t vtbase = ((size_t)(b * H_ + h)) * HS_ * T_;

    bf16x8 qa[2];
    {
        const bf16* qp = U + xbase + (size_t)(q0 + nl) * C_;
        qa[0] = *(const bf16x8*)(qp + kq);
        qa[1] = *(const bf16x8*)(qp + 32 + kq);
    }

    f32x4 o[4] = {f32x4{0,0,0,0}, f32x4{0,0,0,0}, f32x4{0,0,0,0}, f32x4{0,0,0,0}};
    float lrow[4] = {0.f, 0.f, 0.f, 0.f};
    short* myp = &lds_p[wave][0][0];

    for (int kt = 0; kt <= qt; ++kt) {
        const bool diag = (kt == qt);

        // S = Q.K^T
        f32x4 s[4];
#pragma unroll
        for (int t = 0; t < 4; ++t) {
            s[t] = f32x4{0, 0, 0, 0};
            if (!diag || t <= tmax) {
                const bf16* kp = Xb + xbase + (size_t)(kt * 64 + t * 16 + nl) * C_;
                bf16x8 k0v = *(const bf16x8*)(kp + kq);
                bf16x8 k1v = *(const bf16x8*)(kp + 32 + kq);
                s[t] = __builtin_amdgcn_mfma_f32_16x16x32_bf16(qa[0], k0v, s[t], 0, 0, 0);
                s[t] = __builtin_amdgcn_mfma_f32_16x16x32_bf16(qa[1], k1v, s[t], 0, 0, 0);
            }
        }

        // p = exp(s*scale) (no shift), accumulate l, pack P to LDS (A-layout src)
#pragma unroll
        for (int t = 0; t < 4; ++t) {
#pragma unroll
            for (int r = 0; r < 4; ++r) {
                float p;
                if (diag) {
                    const int gk = kt * 64 + t * 16 + nl;
                    const int gq = q0 + quad * 4 + r;
                    p = (t > tmax || gk > gq) ? 0.f : __expf(s[t][r] * SCALE_);
                } else {
                    p = __expf(s[t][r] * SCALE_);
                }
                lrow[r] += p;
                myp[(quad * 4 + r) * 72 + t * 16 + nl] = bf16bits(p);
            }
        }

        bf16x8 pa0 = *(const bf16x8*)&myp[nl * 72 + kq];
        bf16x8 pa1 = *(const bf16x8*)&myp[nl * 72 + 32 + kq];

        // O += P.V  (Vt: contiguous along keys)
#pragma unroll
        for (int t = 0; t < 4; ++t) {
            const bf16* vp = Vt + vtbase + (size_t)(t * 16 + nl) * T_ + kt * 64;
            o[t] = __builtin_amdgcn_mfma_f32_16x16x32_bf16(pa0, *(const bf16x8*)(vp + kq), o[t], 0, 0, 0);
            o[t] = __builtin_amdgcn_mfma_f32_16x16x32_bf16(pa1, *(const bf16x8*)(vp + 32 + kq), o[t], 0, 0, 0);
        }
    }

    // reduce l across the 16-lane col group (row r lives on fixed quad)
#pragma unroll
    for (int r = 0; r < 4; ++r) {
        float v = lrow[r];
        v += __shfl_xor(v, 1, 64);
        v += __shfl_xor(v, 2, 64);
        v += __shfl_xor(v, 4, 64);
        v += __shfl_xor(v, 8, 64);
        lrow[r] = v;
    }

#pragma unroll
    for (int r = 0; r < 4; ++r) {
        const float inv_l = 1.f / lrow[r];
        const size_t yrow = xbase + (size_t)(q0 + quad * 4 + r) * C_;
#pragma unroll
        for (int t = 0; t < 4; ++t)
            Y[yrow + t * 16 + nl] = __float2bfloat16(o[t][r] * inv_l);
    }
}

extern "C" void kernel_launch(void* const* d_in, const int* in_sizes, int n_in,
                              void* d_out, int out_size, void* d_ws, size_t ws_size,
                              hipStream_t stream) {
    const float* x   = (const float*)d_in[0];
    const float* w_u = (const float*)d_in[1];
    const float* b_u = (const float*)d_in[2];
    const float* w_v = (const float*)d_in[3];
    const float* b_v = (const float*)d_in[4];
    const float* w_p = (const float*)d_in[5];
    const float* b_p = (const float*)d_in[6];
    float* out = (float*)d_out;

    char* ws = (char*)d_ws;
    const size_t slab = (size_t)XN_ * sizeof(bf16);   // 6291456
    bf16* Xb  = (bf16*)(ws);
    bf16* U   = (bf16*)(ws + slab);
    bf16* Vt  = (bf16*)(ws + 2 * slab);
    bf16* Yw  = (bf16*)(ws + 3 * slab);
    bf16* Wub = (bf16*)(ws + 4 * slab);
    bf16* Wvb = (bf16*)(ws + 4 * slab + (size_t)WN_ * 2);
    bf16* Wpb = (bf16*)(ws + 4 * slab + (size_t)WN_ * 4);

    dim3 blk(256);
    cvt_all<<<(XN_ + 3 * WN_) / 1024, blk, 0, stream>>>(x, w_u, w_v, w_p, Xb, Wub, Wvb, Wpb);

    dim3 ggrid(M_ / 64, C_ / 64);   // (64, 12)
    gemm_lds<bf16, 0><<<ggrid, blk, 0, stream>>>(Xb, Wub, b_u, U,  M_, C_, C_);
    gemm_lds<bf16, 1><<<ggrid, blk, 0, stream>>>(Xb, Wvb, b_v, Vt, M_, C_, C_);

    dim3 agrid(T_ / 64, H_, B_);    // (32, 12, 2)
    flash_attn<<<agrid, blk, 0, stream>>>(U, Xb, Vt, Yw);

    gemm_lds<float, 0><<<ggrid, blk, 0, stream>>>(Yw, Wpb, b_p, out, M_, C_, C_);
}